// Round 2
// baseline (1578.378 us; speedup 1.0000x reference)
//
#include <hip/hip_runtime.h>

#define DD 128

// ---------------------------------------------------------------------------
// K1: per-node dot products s[n] = h[n]·aw_src, t[n] = h[n]·aw_dst
// one 64-lane wave per node, 2 floats per lane
// ---------------------------------------------------------------------------
__global__ __launch_bounds__(256) void k_node_dots(
    const float* __restrict__ h, const float* __restrict__ attn_w,
    float* __restrict__ s, float* __restrict__ t, int n_nodes)
{
    int gid  = blockIdx.x * blockDim.x + threadIdx.x;
    int node = gid >> 6;
    int lane = threadIdx.x & 63;
    if (node >= n_nodes) return;
    const float2 hv = *reinterpret_cast<const float2*>(h + (size_t)node * DD + lane * 2);
    const float2 as = *reinterpret_cast<const float2*>(attn_w + lane * 2);
    const float2 ad = *reinterpret_cast<const float2*>(attn_w + DD + lane * 2);
    float sa = hv.x * as.x + hv.y * as.y;
    float ta = hv.x * ad.x + hv.y * ad.y;
    #pragma unroll
    for (int off = 32; off > 0; off >>= 1) {
        sa += __shfl_down(sa, off);
        ta += __shfl_down(ta, off);
    }
    if (lane == 0) { s[node] = sa; t[node] = ta; }
}

// ---------------------------------------------------------------------------
// K2: per-edge score e = relu(s[src]+t[dst]+b); store raw score in p_buf;
// segment-max via native uint atomicMax (valid: e >= 0, emax pre-zeroed)
// ---------------------------------------------------------------------------
__global__ __launch_bounds__(256) void k_edge_max(
    const float* __restrict__ s, const float* __restrict__ t,
    const int* __restrict__ src, const int* __restrict__ dst,
    const float* __restrict__ attn_b, float* __restrict__ emax,
    float* __restrict__ p, int n_edges)
{
    int e = blockIdx.x * blockDim.x + threadIdx.x;
    if (e >= n_edges) return;
    int d = dst[e];
    float v = fmaxf(s[src[e]] + t[d] + attn_b[0], 0.f);
    p[e] = v;
    atomicMax(reinterpret_cast<unsigned int*>(emax) + d, __float_as_uint(v));
}

// ---------------------------------------------------------------------------
// K3: per-edge p = exp(e - emax[dst]); denom[dst] += p  (native f32 atomic)
// ---------------------------------------------------------------------------
__global__ __launch_bounds__(256) void k_edge_exp(
    const int* __restrict__ dst, const float* __restrict__ emax,
    float* __restrict__ p, float* __restrict__ denom, int n_edges)
{
    int e = blockIdx.x * blockDim.x + threadIdx.x;
    if (e >= n_edges) return;
    int d = dst[e];
    float pe = expf(p[e] - emax[d]);
    p[e] = pe;
    unsafeAtomicAdd(denom + d, pe);
}

// ---------------------------------------------------------------------------
// K4: scatter u[dst] += p * ef   (32 threads per edge, float4 each,
// native global_atomic_add_f32 via unsafeAtomicAdd)
// ---------------------------------------------------------------------------
__global__ __launch_bounds__(256) void k_scatter(
    const float* __restrict__ ef, const int* __restrict__ dst,
    const float* __restrict__ p, float* __restrict__ u, int n_edges)
{
    int gid = blockIdx.x * blockDim.x + threadIdx.x;
    int e = gid >> 5;
    int q = gid & 31;
    if (e >= n_edges) return;
    float pe = p[e];
    float4 v = *reinterpret_cast<const float4*>(ef + (size_t)e * DD + q * 4);
    float* up = u + (size_t)dst[e] * DD + q * 4;
    unsafeAtomicAdd(up + 0, pe * v.x);
    unsafeAtomicAdd(up + 1, pe * v.y);
    unsafeAtomicAdd(up + 2, pe * v.z);
    unsafeAtomicAdd(up + 3, pe * v.w);
}

// ---------------------------------------------------------------------------
// K5: out[n] = relu([h[n], u[n]/denom[n]] @ W^T + b)
// 16 nodes / block, hz staged in LDS, thread owns (k, 8 nodes)
// ---------------------------------------------------------------------------
__global__ __launch_bounds__(256) void k_apply(
    const float* __restrict__ h, const float* __restrict__ u,
    const float* __restrict__ denom,
    const float* __restrict__ W, const float* __restrict__ b,
    float* __restrict__ out, int n_nodes)
{
    __shared__ float4 hz[16][64];   // 16 nodes x 256 floats (h | z)
    int n0  = blockIdx.x * 16;
    int tid = threadIdx.x;
    #pragma unroll
    for (int it = 0; it < 4; ++it) {
        int idx = tid + it * 256;       // 0..1023
        int n   = idx >> 6;
        int q   = idx & 63;
        int node = n0 + n;
        float4 v = make_float4(0.f, 0.f, 0.f, 0.f);
        if (node < n_nodes) {
            if (q < 32) {
                v = *reinterpret_cast<const float4*>(h + (size_t)node * DD + q * 4);
            } else {
                float dn  = denom[node];
                float inv = dn > 0.f ? 1.f / dn : 0.f;
                float4 uu = *reinterpret_cast<const float4*>(u + (size_t)node * DD + (q - 32) * 4);
                v = make_float4(uu.x * inv, uu.y * inv, uu.z * inv, uu.w * inv);
            }
        }
        hz[n][q] = v;
    }
    __syncthreads();

    int k = tid & 127;
    int g = tid >> 7;                 // node half: g*8 .. g*8+7
    float acc[8] = {0.f, 0.f, 0.f, 0.f, 0.f, 0.f, 0.f, 0.f};
    const float* wr = W + (size_t)k * (2 * DD);
    #pragma unroll 4
    for (int q = 0; q < 64; ++q) {
        float4 w4 = *reinterpret_cast<const float4*>(wr + q * 4);
        #pragma unroll
        for (int i = 0; i < 8; ++i) {
            float4 x = hz[g * 8 + i][q];   // same addr across wave -> broadcast
            acc[i] = fmaf(w4.x, x.x, fmaf(w4.y, x.y, fmaf(w4.z, x.z, fmaf(w4.w, x.w, acc[i]))));
        }
    }
    float bk = b[k];
    #pragma unroll
    for (int i = 0; i < 8; ++i) {
        int node = n0 + g * 8 + i;
        if (node < n_nodes)
            out[(size_t)node * DD + k] = fmaxf(acc[i] + bk, 0.f);
    }
}

// ---------------------------------------------------------------------------
extern "C" void kernel_launch(void* const* d_in, const int* in_sizes, int n_in,
                              void* d_out, int out_size, void* d_ws, size_t ws_size,
                              hipStream_t stream)
{
    const float* nfeats = (const float*)d_in[0];
    const float* efeats = (const float*)d_in[1];
    const float* W      = (const float*)d_in[2];
    const float* Wb     = (const float*)d_in[3];
    const float* attn_w = (const float*)d_in[4];
    const float* attn_b = (const float*)d_in[5];
    const int*   src    = (const int*)d_in[6];
    const int*   dst    = (const int*)d_in[7];

    const int n_nodes = in_sizes[0] / DD;
    const int n_edges = in_sizes[6];

    float* ws    = (float*)d_ws;
    float* s_buf = ws;                      // N
    float* t_buf = s_buf + n_nodes;         // N
    float* emax  = t_buf + n_nodes;         // N
    float* denom = emax + n_nodes;          // N
    float* p_buf = denom + n_nodes;         // E
    float* u_buf = p_buf + n_edges;         // N*128
    float* out   = (float*)d_out;

    // zero emax + denom (contiguous) and the z-accumulator
    hipMemsetAsync(emax, 0, (size_t)2 * n_nodes * sizeof(float), stream);
    hipMemsetAsync(u_buf, 0, (size_t)n_nodes * DD * sizeof(float), stream);

    k_node_dots<<<(n_nodes + 3) / 4, 256, 0, stream>>>(nfeats, attn_w, s_buf, t_buf, n_nodes);
    k_edge_max<<<(n_edges + 255) / 256, 256, 0, stream>>>(s_buf, t_buf, src, dst, attn_b, emax, p_buf, n_edges);
    k_edge_exp<<<(n_edges + 255) / 256, 256, 0, stream>>>(dst, emax, p_buf, denom, n_edges);

    long long scatter_threads = (long long)n_edges * 32;
    int scatter_blocks = (int)((scatter_threads + 255) / 256);
    k_scatter<<<scatter_blocks, 256, 0, stream>>>(efeats, dst, p_buf, u_buf, n_edges);

    k_apply<<<(n_nodes + 15) / 16, 256, 0, stream>>>(nfeats, u_buf, denom, W, Wb, out, n_nodes);
}

// Round 3
// 308.181 us; speedup vs baseline: 5.1216x; 5.1216x over previous
//
#include <hip/hip_runtime.h>

#define DD 128

// ---------------------------------------------------------------------------
// K1: per-node dot products s[n] = h[n]·aw_src, t[n] = h[n]·aw_dst
// ---------------------------------------------------------------------------
__global__ __launch_bounds__(256) void k_node_dots(
    const float* __restrict__ h, const float* __restrict__ attn_w,
    float* __restrict__ s, float* __restrict__ t, int n_nodes)
{
    int gid  = blockIdx.x * blockDim.x + threadIdx.x;
    int node = gid >> 6;
    int lane = threadIdx.x & 63;
    if (node >= n_nodes) return;
    const float2 hv = *reinterpret_cast<const float2*>(h + (size_t)node * DD + lane * 2);
    const float2 as = *reinterpret_cast<const float2*>(attn_w + lane * 2);
    const float2 ad = *reinterpret_cast<const float2*>(attn_w + DD + lane * 2);
    float sa = hv.x * as.x + hv.y * as.y;
    float ta = hv.x * ad.x + hv.y * ad.y;
    #pragma unroll
    for (int off = 32; off > 0; off >>= 1) {
        sa += __shfl_down(sa, off);
        ta += __shfl_down(ta, off);
    }
    if (lane == 0) { s[node] = sa; t[node] = ta; }
}

// ---------------------------------------------------------------------------
// K2: histogram + per-edge rank (native int atomics)
// ---------------------------------------------------------------------------
__global__ __launch_bounds__(256) void k_hist(
    const int* __restrict__ dst, int* __restrict__ count,
    int* __restrict__ rank, int n_edges)
{
    int e = blockIdx.x * blockDim.x + threadIdx.x;
    if (e >= n_edges) return;
    rank[e] = atomicAdd(count + dst[e], 1);
}

// ---------------------------------------------------------------------------
// K3a: per-block partial sums of count
// ---------------------------------------------------------------------------
__global__ __launch_bounds__(256) void k_scan_bsum(
    const int* __restrict__ count, int* __restrict__ bsum, int n)
{
    __shared__ int sm[256];
    int tid = threadIdx.x;
    int idx = blockIdx.x * 256 + tid;
    int v = (idx < n) ? count[idx] : 0;
    sm[tid] = v; __syncthreads();
    for (int off = 128; off > 0; off >>= 1) {
        if (tid < off) sm[tid] += sm[tid + off];
        __syncthreads();
    }
    if (tid == 0) bsum[blockIdx.x] = sm[0];
}

// ---------------------------------------------------------------------------
// K3b: single-block exclusive scan of bsum (loop with carry); also writes
// offset[n_nodes] = n_edges
// ---------------------------------------------------------------------------
__global__ __launch_bounds__(256) void k_scan_carry(
    int* __restrict__ bsum, int nb, int* __restrict__ offset,
    int n_nodes, int n_edges)
{
    __shared__ int sm[256];
    int tid = threadIdx.x;
    int carry = 0;
    for (int base = 0; base < nb; base += 256) {
        int idx = base + tid;
        int v = (idx < nb) ? bsum[idx] : 0;
        sm[tid] = v; __syncthreads();
        for (int off = 1; off < 256; off <<= 1) {
            int t2 = (tid >= off) ? sm[tid - off] : 0;
            __syncthreads();
            sm[tid] += t2;
            __syncthreads();
        }
        if (idx < nb) bsum[idx] = carry + sm[tid] - v;   // exclusive
        carry += sm[255];
        __syncthreads();
    }
    if (tid == 0) offset[n_nodes] = n_edges;
}

// ---------------------------------------------------------------------------
// K3c: per-block exclusive scan + block offset -> offset[]
// ---------------------------------------------------------------------------
__global__ __launch_bounds__(256) void k_scan_final(
    const int* __restrict__ count, const int* __restrict__ boff,
    int* __restrict__ offset, int n)
{
    __shared__ int sm[256];
    int tid = threadIdx.x;
    int idx = blockIdx.x * 256 + tid;
    int v = (idx < n) ? count[idx] : 0;
    sm[tid] = v; __syncthreads();
    for (int off = 1; off < 256; off <<= 1) {
        int t2 = (tid >= off) ? sm[tid - off] : 0;
        __syncthreads();
        sm[tid] += t2;
        __syncthreads();
    }
    if (idx < n) offset[idx] = boff[blockIdx.x] + sm[tid] - v;
}

// ---------------------------------------------------------------------------
// K4: scatter edge ids into dst-sorted order
// ---------------------------------------------------------------------------
__global__ __launch_bounds__(256) void k_scatter_ids(
    const int* __restrict__ dst, const int* __restrict__ rank,
    const int* __restrict__ offset, int* __restrict__ order, int n_edges)
{
    int e = blockIdx.x * blockDim.x + threadIdx.x;
    if (e >= n_edges) return;
    order[offset[dst[e]] + rank[e]] = e;
}

// ---------------------------------------------------------------------------
// K5: fused per-node attention: scores -> max -> exp/sum -> weighted gather.
// One 64-lane wave per node; zero global atomics; u written once, normalized.
// ---------------------------------------------------------------------------
__global__ __launch_bounds__(256) void k_fused(
    const float* __restrict__ s, const float* __restrict__ t,
    const float* __restrict__ attn_b,
    const int* __restrict__ src, const int* __restrict__ offset,
    const int* __restrict__ order, const float* __restrict__ ef,
    float* __restrict__ p_buf, float* __restrict__ u, int n_nodes)
{
    int node = blockIdx.x * (blockDim.x >> 6) + (threadIdx.x >> 6);
    int lane = threadIdx.x & 63;
    if (node >= n_nodes) return;
    int beg = offset[node];
    int end = offset[node + 1];
    int deg = end - beg;
    float tn = t[node] + attn_b[0];

    // phase 1: scores (relu >= 0, so max over empty/partial lanes = 0 is safe)
    float m = 0.f;
    for (int i = lane; i < deg; i += 64) {
        int e = order[beg + i];
        float sc = fmaxf(s[src[e]] + tn, 0.f);
        p_buf[beg + i] = sc;
        m = fmaxf(m, sc);
    }
    #pragma unroll
    for (int off = 32; off > 0; off >>= 1) m = fmaxf(m, __shfl_xor(m, off));

    // phase 2: exp + sum
    float sum = 0.f;
    for (int i = lane; i < deg; i += 64) {
        float pe = expf(p_buf[beg + i] - m);
        p_buf[beg + i] = pe;
        sum += pe;
    }
    #pragma unroll
    for (int off = 32; off > 0; off >>= 1) sum += __shfl_xor(sum, off);
    float inv = sum > 0.f ? 1.f / sum : 0.f;

    // phase 3: z = sum_e alpha_e * ef[e]; lane owns dims {2*lane, 2*lane+1}
    float2 acc = make_float2(0.f, 0.f);
    for (int i0 = 0; i0 < deg; i0 += 64) {
        int cnt = min(64, deg - i0);
        int   e_l = (lane < cnt) ? order[beg + i0 + lane] : 0;
        float p_l = (lane < cnt) ? p_buf[beg + i0 + lane] * inv : 0.f;
        for (int j = 0; j < cnt; ++j) {
            int   e  = __shfl(e_l, j);
            float pw = __shfl(p_l, j);
            float2 v = *reinterpret_cast<const float2*>(ef + (size_t)e * DD + lane * 2);
            acc.x = fmaf(pw, v.x, acc.x);
            acc.y = fmaf(pw, v.y, acc.y);
        }
    }
    *reinterpret_cast<float2*>(u + (size_t)node * DD + lane * 2) = acc;
}

// ---------------------------------------------------------------------------
// K6: out[n] = relu([h[n], z[n]] @ W^T + b)   (z already normalized)
// ---------------------------------------------------------------------------
__global__ __launch_bounds__(256) void k_apply(
    const float* __restrict__ h, const float* __restrict__ u,
    const float* __restrict__ W, const float* __restrict__ b,
    float* __restrict__ out, int n_nodes)
{
    __shared__ float4 hz[16][64];   // 16 nodes x 256 floats (h | z)
    int n0  = blockIdx.x * 16;
    int tid = threadIdx.x;
    #pragma unroll
    for (int it = 0; it < 4; ++it) {
        int idx = tid + it * 256;       // 0..1023
        int n   = idx >> 6;
        int q   = idx & 63;
        int node = n0 + n;
        float4 v = make_float4(0.f, 0.f, 0.f, 0.f);
        if (node < n_nodes) {
            if (q < 32) v = *reinterpret_cast<const float4*>(h + (size_t)node * DD + q * 4);
            else        v = *reinterpret_cast<const float4*>(u + (size_t)node * DD + (q - 32) * 4);
        }
        hz[n][q] = v;
    }
    __syncthreads();

    int k = tid & 127;
    int g = tid >> 7;
    float acc[8] = {0.f, 0.f, 0.f, 0.f, 0.f, 0.f, 0.f, 0.f};
    const float* wr = W + (size_t)k * (2 * DD);
    #pragma unroll 4
    for (int q = 0; q < 64; ++q) {
        float4 w4 = *reinterpret_cast<const float4*>(wr + q * 4);
        #pragma unroll
        for (int i = 0; i < 8; ++i) {
            float4 x = hz[g * 8 + i][q];   // broadcast across wave
            acc[i] = fmaf(w4.x, x.x, fmaf(w4.y, x.y, fmaf(w4.z, x.z, fmaf(w4.w, x.w, acc[i]))));
        }
    }
    float bk = b[k];
    #pragma unroll
    for (int i = 0; i < 8; ++i) {
        int node = n0 + g * 8 + i;
        if (node < n_nodes)
            out[(size_t)node * DD + k] = fmaxf(acc[i] + bk, 0.f);
    }
}

// ---------------------------------------------------------------------------
extern "C" void kernel_launch(void* const* d_in, const int* in_sizes, int n_in,
                              void* d_out, int out_size, void* d_ws, size_t ws_size,
                              hipStream_t stream)
{
    const float* nfeats = (const float*)d_in[0];
    const float* efeats = (const float*)d_in[1];
    const float* W      = (const float*)d_in[2];
    const float* Wb     = (const float*)d_in[3];
    const float* attn_w = (const float*)d_in[4];
    const float* attn_b = (const float*)d_in[5];
    const int*   src    = (const int*)d_in[6];
    const int*   dst    = (const int*)d_in[7];

    const int n_nodes = in_sizes[0] / DD;
    const int n_edges = in_sizes[6];
    const int NB = (n_nodes + 255) / 256;    // scan blocks

    // workspace layout
    char* wsb = (char*)d_ws;
    float* s_buf  = (float*)wsb;                         wsb += (size_t)n_nodes * 4;
    float* t_buf  = (float*)wsb;                         wsb += (size_t)n_nodes * 4;
    int*   count  = (int*)wsb;                           wsb += (size_t)n_nodes * 4;
    int*   offset = (int*)wsb;                           wsb += (size_t)(n_nodes + 1) * 4;
    int*   bsum   = (int*)wsb;                           wsb += (size_t)((NB + 63) & ~63) * 4;
    int*   order  = (int*)wsb;                           wsb += (size_t)n_edges * 4;
    float* p_buf  = (float*)wsb;                         wsb += (size_t)n_edges * 4;
    float* u_buf  = (float*)wsb;                         // N*128 f32
    int*   rank   = (int*)u_buf;                         // aliased: dead before u written

    hipMemsetAsync(count, 0, (size_t)n_nodes * 4, stream);

    k_node_dots<<<(n_nodes + 3) / 4, 256, 0, stream>>>(nfeats, attn_w, s_buf, t_buf, n_nodes);
    k_hist<<<(n_edges + 255) / 256, 256, 0, stream>>>(dst, count, rank, n_edges);
    k_scan_bsum<<<NB, 256, 0, stream>>>(count, bsum, n_nodes);
    k_scan_carry<<<1, 256, 0, stream>>>(bsum, NB, offset, n_nodes, n_edges);
    k_scan_final<<<NB, 256, 0, stream>>>(count, bsum, offset, n_nodes);
    k_scatter_ids<<<(n_edges + 255) / 256, 256, 0, stream>>>(dst, rank, offset, order, n_edges);

    k_fused<<<(n_nodes + 3) / 4, 256, 0, stream>>>(s_buf, t_buf, attn_b, src, offset,
                                                   order, efeats, p_buf, u_buf, n_nodes);

    k_apply<<<(n_nodes + 15) / 16, 256, 0, stream>>>(nfeats, u_buf, W, Wb, (float*)d_out, n_nodes);
}

// Round 5
// 279.437 us; speedup vs baseline: 5.6484x; 1.1029x over previous
//
#include <hip/hip_runtime.h>

#define DD 128

// ---------------------------------------------------------------------------
// K1: per-node dot products s[n] = h[n]·aw_src, t[n] = h[n]·aw_dst
// ---------------------------------------------------------------------------
__global__ __launch_bounds__(256) void k_node_dots(
    const float* __restrict__ h, const float* __restrict__ attn_w,
    float* __restrict__ s, float* __restrict__ t, int n_nodes)
{
    int gid  = blockIdx.x * blockDim.x + threadIdx.x;
    int node = gid >> 6;
    int lane = threadIdx.x & 63;
    if (node >= n_nodes) return;
    const float2 hv = *reinterpret_cast<const float2*>(h + (size_t)node * DD + lane * 2);
    const float2 as = *reinterpret_cast<const float2*>(attn_w + lane * 2);
    const float2 ad = *reinterpret_cast<const float2*>(attn_w + DD + lane * 2);
    float sa = hv.x * as.x + hv.y * as.y;
    float ta = hv.x * ad.x + hv.y * ad.y;
    #pragma unroll
    for (int off = 32; off > 0; off >>= 1) {
        sa += __shfl_down(sa, off);
        ta += __shfl_down(ta, off);
    }
    if (lane == 0) { s[node] = sa; t[node] = ta; }
}

// ---------------------------------------------------------------------------
// K2: histogram + per-edge rank (native int atomics)
// ---------------------------------------------------------------------------
__global__ __launch_bounds__(256) void k_hist(
    const int* __restrict__ dst, int* __restrict__ count,
    int* __restrict__ rank, int n_edges)
{
    int e = blockIdx.x * blockDim.x + threadIdx.x;
    if (e >= n_edges) return;
    rank[e] = atomicAdd(count + dst[e], 1);
}

// ---------------------------------------------------------------------------
// K3a: per-block partial sums of count
// ---------------------------------------------------------------------------
__global__ __launch_bounds__(256) void k_scan_bsum(
    const int* __restrict__ count, int* __restrict__ bsum, int n)
{
    __shared__ int sm[256];
    int tid = threadIdx.x;
    int idx = blockIdx.x * 256 + tid;
    int v = (idx < n) ? count[idx] : 0;
    sm[tid] = v; __syncthreads();
    for (int off = 128; off > 0; off >>= 1) {
        if (tid < off) sm[tid] += sm[tid + off];
        __syncthreads();
    }
    if (tid == 0) bsum[blockIdx.x] = sm[0];
}

// ---------------------------------------------------------------------------
// K3b: single-block exclusive scan of bsum (loop with carry); also writes
// offset[n_nodes] = n_edges
// ---------------------------------------------------------------------------
__global__ __launch_bounds__(256) void k_scan_carry(
    int* __restrict__ bsum, int nb, int* __restrict__ offset,
    int n_nodes, int n_edges)
{
    __shared__ int sm[256];
    int tid = threadIdx.x;
    int carry = 0;
    for (int base = 0; base < nb; base += 256) {
        int idx = base + tid;
        int v = (idx < nb) ? bsum[idx] : 0;
        sm[tid] = v; __syncthreads();
        for (int off = 1; off < 256; off <<= 1) {
            int t2 = (tid >= off) ? sm[tid - off] : 0;
            __syncthreads();
            sm[tid] += t2;
            __syncthreads();
        }
        if (idx < nb) bsum[idx] = carry + sm[tid] - v;   // exclusive
        carry += sm[255];
        __syncthreads();
    }
    if (tid == 0) offset[n_nodes] = n_edges;
}

// ---------------------------------------------------------------------------
// K3c: per-block exclusive scan + block offset -> offset[]
// ---------------------------------------------------------------------------
__global__ __launch_bounds__(256) void k_scan_final(
    const int* __restrict__ count, const int* __restrict__ boff,
    int* __restrict__ offset, int n)
{
    __shared__ int sm[256];
    int tid = threadIdx.x;
    int idx = blockIdx.x * 256 + tid;
    int v = (idx < n) ? count[idx] : 0;
    sm[tid] = v; __syncthreads();
    for (int off = 1; off < 256; off <<= 1) {
        int t2 = (tid >= off) ? sm[tid - off] : 0;
        __syncthreads();
        sm[tid] += t2;
        __syncthreads();
    }
    if (idx < n) offset[idx] = boff[blockIdx.x] + sm[tid] - v;
}

// ---------------------------------------------------------------------------
// K4: scatter edge ids into dst-sorted order
// ---------------------------------------------------------------------------
__global__ __launch_bounds__(256) void k_scatter_ids(
    const int* __restrict__ dst, const int* __restrict__ rank,
    const int* __restrict__ offset, int* __restrict__ order, int n_edges)
{
    int e = blockIdx.x * blockDim.x + threadIdx.x;
    if (e >= n_edges) return;
    order[offset[dst[e]] + rank[e]] = e;
}

// ---------------------------------------------------------------------------
// K5: fused per-node attention. One 64-lane wave per node, zero atomics.
// Fast path (deg <= 64): registers only; phase 3 runs 4 edges concurrently
// (4 groups of 16 lanes, lane owns 8 dims). NOTE: phase-3 loop bound is
// wave-UNIFORM (kmax) so every __shfl reads from an ACTIVE lane — a
// divergent-exit shfl here is undefined and was the round-4 bug.
// ---------------------------------------------------------------------------
__global__ __launch_bounds__(256) void k_fused(
    const float* __restrict__ s, const float* __restrict__ t,
    const float* __restrict__ attn_b,
    const int* __restrict__ src, const int* __restrict__ offset,
    const int* __restrict__ order, const float* __restrict__ ef,
    float* __restrict__ p_buf, float* __restrict__ u, int n_nodes)
{
    int node = blockIdx.x * (blockDim.x >> 6) + (threadIdx.x >> 6);
    int lane = threadIdx.x & 63;
    if (node >= n_nodes) return;
    int beg = offset[node];
    int deg = offset[node + 1] - beg;
    float tn = t[node] + attn_b[0];

    if (deg <= 64) {
        // ---- registers-only path: lane i holds edge i ----
        int   e_l = 0;
        float sc  = 0.f;
        if (lane < deg) {
            e_l = order[beg + lane];
            sc  = fmaxf(s[src[e_l]] + tn, 0.f);
        }
        float m = sc;
        #pragma unroll
        for (int off = 32; off > 0; off >>= 1) m = fmaxf(m, __shfl_xor(m, off));
        float pe = (lane < deg) ? expf(sc - m) : 0.f;
        float sum = pe;
        #pragma unroll
        for (int off = 32; off > 0; off >>= 1) sum += __shfl_xor(sum, off);
        float inv  = sum > 0.f ? 1.f / sum : 0.f;
        float pw_l = pe * inv;

        // phase 3: group g (lanes 16g..16g+15) processes edges g, g+4, g+8, ...
        // lane owns dims [8*sub, 8*sub+8). Uniform trip count for shfl safety.
        int grp = lane >> 4, sub = lane & 15;
        float4 a0 = make_float4(0.f, 0.f, 0.f, 0.f);
        float4 a1 = make_float4(0.f, 0.f, 0.f, 0.f);
        int kmax = (deg + 3) >> 2;
        for (int k = 0; k < kmax; ++k) {
            int j   = grp + 4 * k;
            int jj  = (j < deg) ? j : 0;          // valid (active) source lane
            int   e  = __shfl(e_l, jj);
            float pw = __shfl(pw_l, jj);
            if (j >= deg) pw = 0.f;               // tail: contributes nothing
            const float4* er = reinterpret_cast<const float4*>(ef + (size_t)e * DD + sub * 8);
            float4 v0 = er[0];
            float4 v1 = er[1];
            a0.x = fmaf(pw, v0.x, a0.x); a0.y = fmaf(pw, v0.y, a0.y);
            a0.z = fmaf(pw, v0.z, a0.z); a0.w = fmaf(pw, v0.w, a0.w);
            a1.x = fmaf(pw, v1.x, a1.x); a1.y = fmaf(pw, v1.y, a1.y);
            a1.z = fmaf(pw, v1.z, a1.z); a1.w = fmaf(pw, v1.w, a1.w);
        }
        // combine the 4 groups (lanes sub, sub+16, sub+32, sub+48 share dims)
        #pragma unroll
        for (int off = 16; off <= 32; off <<= 1) {
            a0.x += __shfl_xor(a0.x, off); a0.y += __shfl_xor(a0.y, off);
            a0.z += __shfl_xor(a0.z, off); a0.w += __shfl_xor(a0.w, off);
            a1.x += __shfl_xor(a1.x, off); a1.y += __shfl_xor(a1.y, off);
            a1.z += __shfl_xor(a1.z, off); a1.w += __shfl_xor(a1.w, off);
        }
        if (lane < 16) {
            float4* ur = reinterpret_cast<float4*>(u + (size_t)node * DD + sub * 8);
            ur[0] = a0;
            ur[1] = a1;
        }
    } else {
        // ---- general path (rare): spill scores to p_buf ----
        float mx = 0.f;
        for (int i = lane; i < deg; i += 64) {
            int e = order[beg + i];
            float sc = fmaxf(s[src[e]] + tn, 0.f);
            p_buf[beg + i] = sc;
            mx = fmaxf(mx, sc);
        }
        #pragma unroll
        for (int off = 32; off > 0; off >>= 1) mx = fmaxf(mx, __shfl_xor(mx, off));
        float sum = 0.f;
        for (int i = lane; i < deg; i += 64) {
            float pe = expf(p_buf[beg + i] - mx);
            p_buf[beg + i] = pe;
            sum += pe;
        }
        #pragma unroll
        for (int off = 32; off > 0; off >>= 1) sum += __shfl_xor(sum, off);
        float inv = sum > 0.f ? 1.f / sum : 0.f;

        float2 acc = make_float2(0.f, 0.f);
        for (int i0 = 0; i0 < deg; i0 += 64) {
            int cnt = min(64, deg - i0);          // wave-uniform bound
            int   e_l = (lane < cnt) ? order[beg + i0 + lane] : 0;
            float p_l = (lane < cnt) ? p_buf[beg + i0 + lane] * inv : 0.f;
            for (int j = 0; j < cnt; ++j) {
                int   e  = __shfl(e_l, j);
                float pw = __shfl(p_l, j);
                float2 v = *reinterpret_cast<const float2*>(ef + (size_t)e * DD + lane * 2);
                acc.x = fmaf(pw, v.x, acc.x);
                acc.y = fmaf(pw, v.y, acc.y);
            }
        }
        *reinterpret_cast<float2*>(u + (size_t)node * DD + lane * 2) = acc;
    }
}

// ---------------------------------------------------------------------------
// K6: out[n] = relu([h[n], z[n]] @ W^T + b)   (z already normalized)
// ---------------------------------------------------------------------------
__global__ __launch_bounds__(256) void k_apply(
    const float* __restrict__ h, const float* __restrict__ u,
    const float* __restrict__ W, const float* __restrict__ b,
    float* __restrict__ out, int n_nodes)
{
    __shared__ float4 hz[16][64];   // 16 nodes x 256 floats (h | z)
    int n0  = blockIdx.x * 16;
    int tid = threadIdx.x;
    #pragma unroll
    for (int it = 0; it < 4; ++it) {
        int idx = tid + it * 256;       // 0..1023
        int n   = idx >> 6;
        int q   = idx & 63;
        int node = n0 + n;
        float4 v = make_float4(0.f, 0.f, 0.f, 0.f);
        if (node < n_nodes) {
            if (q < 32) v = *reinterpret_cast<const float4*>(h + (size_t)node * DD + q * 4);
            else        v = *reinterpret_cast<const float4*>(u + (size_t)node * DD + (q - 32) * 4);
        }
        hz[n][q] = v;
    }
    __syncthreads();

    int k = tid & 127;
    int g = tid >> 7;
    float acc[8] = {0.f, 0.f, 0.f, 0.f, 0.f, 0.f, 0.f, 0.f};
    const float* wr = W + (size_t)k * (2 * DD);
    #pragma unroll 4
    for (int q = 0; q < 64; ++q) {
        float4 w4 = *reinterpret_cast<const float4*>(wr + q * 4);
        #pragma unroll
        for (int i = 0; i < 8; ++i) {
            float4 x = hz[g * 8 + i][q];   // broadcast across wave
            acc[i] = fmaf(w4.x, x.x, fmaf(w4.y, x.y, fmaf(w4.z, x.z, fmaf(w4.w, x.w, acc[i]))));
        }
    }
    float bk = b[k];
    #pragma unroll
    for (int i = 0; i < 8; ++i) {
        int node = n0 + g * 8 + i;
        if (node < n_nodes)
            out[(size_t)node * DD + k] = fmaxf(acc[i] + bk, 0.f);
    }
}

// ---------------------------------------------------------------------------
extern "C" void kernel_launch(void* const* d_in, const int* in_sizes, int n_in,
                              void* d_out, int out_size, void* d_ws, size_t ws_size,
                              hipStream_t stream)
{
    const float* nfeats = (const float*)d_in[0];
    const float* efeats = (const float*)d_in[1];
    const float* W      = (const float*)d_in[2];
    const float* Wb     = (const float*)d_in[3];
    const float* attn_w = (const float*)d_in[4];
    const float* attn_b = (const float*)d_in[5];
    const int*   src    = (const int*)d_in[6];
    const int*   dst    = (const int*)d_in[7];

    const int n_nodes = in_sizes[0] / DD;
    const int n_edges = in_sizes[6];
    const int NB = (n_nodes + 255) / 256;    // scan blocks

    // workspace layout
    char* wsb = (char*)d_ws;
    float* s_buf  = (float*)wsb;                         wsb += (size_t)n_nodes * 4;
    float* t_buf  = (float*)wsb;                         wsb += (size_t)n_nodes * 4;
    int*   count  = (int*)wsb;                           wsb += (size_t)n_nodes * 4;
    int*   offset = (int*)wsb;                           wsb += (size_t)(n_nodes + 1) * 4;
    int*   bsum   = (int*)wsb;                           wsb += (size_t)((NB + 63) & ~63) * 4;
    int*   order  = (int*)wsb;                           wsb += (size_t)n_edges * 4;
    float* p_buf  = (float*)wsb;                         wsb += (size_t)n_edges * 4;
    float* u_buf  = (float*)wsb;                         // N*128 f32
    int*   rank   = (int*)u_buf;                         // aliased: dead before u written

    hipMemsetAsync(count, 0, (size_t)n_nodes * 4, stream);

    k_node_dots<<<(n_nodes + 3) / 4, 256, 0, stream>>>(nfeats, attn_w, s_buf, t_buf, n_nodes);
    k_hist<<<(n_edges + 255) / 256, 256, 0, stream>>>(dst, count, rank, n_edges);
    k_scan_bsum<<<NB, 256, 0, stream>>>(count, bsum, n_nodes);
    k_scan_carry<<<1, 256, 0, stream>>>(bsum, NB, offset, n_nodes, n_edges);
    k_scan_final<<<NB, 256, 0, stream>>>(count, bsum, offset, n_nodes);
    k_scatter_ids<<<(n_edges + 255) / 256, 256, 0, stream>>>(dst, rank, offset, order, n_edges);

    k_fused<<<(n_nodes + 3) / 4, 256, 0, stream>>>(s_buf, t_buf, attn_b, src, offset,
                                                   order, efeats, p_buf, u_buf, n_nodes);

    k_apply<<<(n_nodes + 15) / 16, 256, 0, stream>>>(nfeats, u_buf, W, Wb, (float*)d_out, n_nodes);
}

// Round 7
// 277.338 us; speedup vs baseline: 5.6912x; 1.0076x over previous
//
#include <hip/hip_runtime.h>

#define DD 128

typedef float vfloat4 __attribute__((ext_vector_type(4)));

__device__ inline float4 ntload4(const float* p) {
    vfloat4 v = __builtin_nontemporal_load(reinterpret_cast<const vfloat4*>(p));
    return make_float4(v.x, v.y, v.z, v.w);
}

// ---------------------------------------------------------------------------
// K1: per-node dot products s[n] = h[n]·aw_src, t[n] = h[n]·aw_dst
// ---------------------------------------------------------------------------
__global__ __launch_bounds__(256) void k_node_dots(
    const float* __restrict__ h, const float* __restrict__ attn_w,
    float* __restrict__ s, float* __restrict__ t, int n_nodes)
{
    int gid  = blockIdx.x * blockDim.x + threadIdx.x;
    int node = gid >> 6;
    int lane = threadIdx.x & 63;
    if (node >= n_nodes) return;
    const float2 hv = *reinterpret_cast<const float2*>(h + (size_t)node * DD + lane * 2);
    const float2 as = *reinterpret_cast<const float2*>(attn_w + lane * 2);
    const float2 ad = *reinterpret_cast<const float2*>(attn_w + DD + lane * 2);
    float sa = hv.x * as.x + hv.y * as.y;
    float ta = hv.x * ad.x + hv.y * ad.y;
    #pragma unroll
    for (int off = 32; off > 0; off >>= 1) {
        sa += __shfl_down(sa, off);
        ta += __shfl_down(ta, off);
    }
    if (lane == 0) { s[node] = sa; t[node] = ta; }
}

// ---------------------------------------------------------------------------
// K2: histogram + per-edge rank (native int atomics)
// ---------------------------------------------------------------------------
__global__ __launch_bounds__(256) void k_hist(
    const int* __restrict__ dst, int* __restrict__ count,
    int* __restrict__ rank, int n_edges)
{
    int e = blockIdx.x * blockDim.x + threadIdx.x;
    if (e >= n_edges) return;
    rank[e] = atomicAdd(count + dst[e], 1);
}

// ---------------------------------------------------------------------------
// K3a: per-block partial sums of count
// ---------------------------------------------------------------------------
__global__ __launch_bounds__(256) void k_scan_bsum(
    const int* __restrict__ count, int* __restrict__ bsum, int n)
{
    __shared__ int sm[256];
    int tid = threadIdx.x;
    int idx = blockIdx.x * 256 + tid;
    int v = (idx < n) ? count[idx] : 0;
    sm[tid] = v; __syncthreads();
    for (int off = 128; off > 0; off >>= 1) {
        if (tid < off) sm[tid] += sm[tid + off];
        __syncthreads();
    }
    if (tid == 0) bsum[blockIdx.x] = sm[0];
}

// ---------------------------------------------------------------------------
// K3b: single-block exclusive scan of bsum; writes offset[n_nodes] = n_edges
// ---------------------------------------------------------------------------
__global__ __launch_bounds__(256) void k_scan_carry(
    int* __restrict__ bsum, int nb, int* __restrict__ offset,
    int n_nodes, int n_edges)
{
    __shared__ int sm[256];
    int tid = threadIdx.x;
    int carry = 0;
    for (int base = 0; base < nb; base += 256) {
        int idx = base + tid;
        int v = (idx < nb) ? bsum[idx] : 0;
        sm[tid] = v; __syncthreads();
        for (int off = 1; off < 256; off <<= 1) {
            int t2 = (tid >= off) ? sm[tid - off] : 0;
            __syncthreads();
            sm[tid] += t2;
            __syncthreads();
        }
        if (idx < nb) bsum[idx] = carry + sm[tid] - v;   // exclusive
        carry += sm[255];
        __syncthreads();
    }
    if (tid == 0) offset[n_nodes] = n_edges;
}

// ---------------------------------------------------------------------------
// K3c: per-block exclusive scan + block offset -> offset[]
// ---------------------------------------------------------------------------
__global__ __launch_bounds__(256) void k_scan_final(
    const int* __restrict__ count, const int* __restrict__ boff,
    int* __restrict__ offset, int n)
{
    __shared__ int sm[256];
    int tid = threadIdx.x;
    int idx = blockIdx.x * 256 + tid;
    int v = (idx < n) ? count[idx] : 0;
    sm[tid] = v; __syncthreads();
    for (int off = 1; off < 256; off <<= 1) {
        int t2 = (tid >= off) ? sm[tid - off] : 0;
        __syncthreads();
        sm[tid] += t2;
        __syncthreads();
    }
    if (idx < n) offset[idx] = boff[blockIdx.x] + sm[tid] - v;
}

// ---------------------------------------------------------------------------
// K4: scatter edge ids into dst-sorted order AND precompute the relu'd
// attention score at the sorted position (moves the random s/t gathers out
// of the hot fused kernel; src/dst/rank reads here are coalesced).
// ---------------------------------------------------------------------------
__global__ __launch_bounds__(256) void k_scatter_ids(
    const int* __restrict__ dst, const int* __restrict__ src,
    const int* __restrict__ rank, const int* __restrict__ offset,
    const float* __restrict__ s, const float* __restrict__ t,
    const float* __restrict__ attn_b,
    int* __restrict__ order, float* __restrict__ score, int n_edges)
{
    int e = blockIdx.x * blockDim.x + threadIdx.x;
    if (e >= n_edges) return;
    int d   = dst[e];
    int pos = offset[d] + rank[e];
    order[pos] = e;
    score[pos] = fmaxf(s[src[e]] + t[d] + attn_b[0], 0.f);
}

// ---------------------------------------------------------------------------
// K5: fused per-node attention. One 64-lane wave per node, zero atomics.
// Fast path (deg <= 64): registers only; phase 3 runs 8 edges concurrently
// (8 groups of 8 lanes, lane owns 16 dims). All __shfl sit OUTSIDE divergent
// branches with wave-uniform loop bounds (round-4 lesson). Tail iterations
// skip the ef loads entirely. ef loads are nontemporal (read-once stream).
// ---------------------------------------------------------------------------
__global__ __launch_bounds__(256) void k_fused(
    const int* __restrict__ offset, const int* __restrict__ order,
    const float* __restrict__ ef,
    float* __restrict__ p_buf,              // holds scores (from K4); slow path overwrites with exp
    float* __restrict__ u, int n_nodes)
{
    int node = blockIdx.x * (blockDim.x >> 6) + (threadIdx.x >> 6);
    int lane = threadIdx.x & 63;
    if (node >= n_nodes) return;
    int beg = offset[node];
    int deg = offset[node + 1] - beg;

    if (deg <= 64) {
        // ---- phase 1+2: contiguous loads, all in registers ----
        int   e_l = 0;
        float sc  = 0.f;
        if (lane < deg) {
            e_l = order[beg + lane];
            sc  = p_buf[beg + lane];
        }
        float m = sc;
        #pragma unroll
        for (int off = 32; off > 0; off >>= 1) m = fmaxf(m, __shfl_xor(m, off));
        float pe = (lane < deg) ? expf(sc - m) : 0.f;
        float sum = pe;
        #pragma unroll
        for (int off = 32; off > 0; off >>= 1) sum += __shfl_xor(sum, off);
        float inv  = sum > 0.f ? 1.f / sum : 0.f;
        float pw_l = pe * inv;

        // ---- phase 3: group g (lanes 8g..8g+7) does edges g, g+8, ... ----
        // lane sub owns float4 indices {sub, 8+sub, 16+sub, 24+sub} of the row
        int grp = lane >> 3, sub = lane & 7;
        float4 a0 = make_float4(0.f, 0.f, 0.f, 0.f);
        float4 a1 = a0, a2 = a0, a3 = a0;
        int kmax = (deg + 7) >> 3;
        for (int k = 0; k < kmax; ++k) {
            int j  = grp + 8 * k;
            int jj = (j < deg) ? j : 0;           // shfl src must be a valid lane
            int   e  = __shfl(e_l, jj);           // uniform-active shfl
            float pw = __shfl(pw_l, jj);
            if (j < deg) {                        // tail: skip loads entirely
                const float* er = ef + (size_t)e * DD;
                float4 v0 = ntload4(er + sub * 4);
                float4 v1 = ntload4(er + 32 + sub * 4);
                float4 v2 = ntload4(er + 64 + sub * 4);
                float4 v3 = ntload4(er + 96 + sub * 4);
                a0.x = fmaf(pw, v0.x, a0.x); a0.y = fmaf(pw, v0.y, a0.y);
                a0.z = fmaf(pw, v0.z, a0.z); a0.w = fmaf(pw, v0.w, a0.w);
                a1.x = fmaf(pw, v1.x, a1.x); a1.y = fmaf(pw, v1.y, a1.y);
                a1.z = fmaf(pw, v1.z, a1.z); a1.w = fmaf(pw, v1.w, a1.w);
                a2.x = fmaf(pw, v2.x, a2.x); a2.y = fmaf(pw, v2.y, a2.y);
                a2.z = fmaf(pw, v2.z, a2.z); a2.w = fmaf(pw, v2.w, a2.w);
                a3.x = fmaf(pw, v3.x, a3.x); a3.y = fmaf(pw, v3.y, a3.y);
                a3.z = fmaf(pw, v3.z, a3.z); a3.w = fmaf(pw, v3.w, a3.w);
            }
        }
        // combine the 8 groups (lanes with equal sub share dims)
        #pragma unroll
        for (int off = 8; off <= 32; off <<= 1) {
            a0.x += __shfl_xor(a0.x, off); a0.y += __shfl_xor(a0.y, off);
            a0.z += __shfl_xor(a0.z, off); a0.w += __shfl_xor(a0.w, off);
            a1.x += __shfl_xor(a1.x, off); a1.y += __shfl_xor(a1.y, off);
            a1.z += __shfl_xor(a1.z, off); a1.w += __shfl_xor(a1.w, off);
            a2.x += __shfl_xor(a2.x, off); a2.y += __shfl_xor(a2.y, off);
            a2.z += __shfl_xor(a2.z, off); a2.w += __shfl_xor(a2.w, off);
            a3.x += __shfl_xor(a3.x, off); a3.y += __shfl_xor(a3.y, off);
            a3.z += __shfl_xor(a3.z, off); a3.w += __shfl_xor(a3.w, off);
        }
        if (lane < 8) {
            float4* ur = reinterpret_cast<float4*>(u + (size_t)node * DD);
            ur[sub]      = a0;
            ur[8 + sub]  = a1;
            ur[16 + sub] = a2;
            ur[24 + sub] = a3;
        }
    } else {
        // ---- general path (rare): scores already in p_buf ----
        float mx = 0.f;
        for (int i = lane; i < deg; i += 64) mx = fmaxf(mx, p_buf[beg + i]);
        #pragma unroll
        for (int off = 32; off > 0; off >>= 1) mx = fmaxf(mx, __shfl_xor(mx, off));
        float sum = 0.f;
        for (int i = lane; i < deg; i += 64) {
            float pe = expf(p_buf[beg + i] - mx);
            p_buf[beg + i] = pe;
            sum += pe;
        }
        #pragma unroll
        for (int off = 32; off > 0; off >>= 1) sum += __shfl_xor(sum, off);
        float inv = sum > 0.f ? 1.f / sum : 0.f;

        float2 acc = make_float2(0.f, 0.f);
        for (int i0 = 0; i0 < deg; i0 += 64) {
            int cnt = min(64, deg - i0);          // wave-uniform bound
            int   e_l = (lane < cnt) ? order[beg + i0 + lane] : 0;
            float p_l = (lane < cnt) ? p_buf[beg + i0 + lane] * inv : 0.f;
            for (int j = 0; j < cnt; ++j) {
                int   e  = __shfl(e_l, j);
                float pw = __shfl(p_l, j);
                float2 v = *reinterpret_cast<const float2*>(ef + (size_t)e * DD + lane * 2);
                acc.x = fmaf(pw, v.x, acc.x);
                acc.y = fmaf(pw, v.y, acc.y);
            }
        }
        *reinterpret_cast<float2*>(u + (size_t)node * DD + lane * 2) = acc;
    }
}

// ---------------------------------------------------------------------------
// K6: out[n] = relu([h[n], z[n]] @ W^T + b)   (z already normalized)
// ---------------------------------------------------------------------------
__global__ __launch_bounds__(256) void k_apply(
    const float* __restrict__ h, const float* __restrict__ u,
    const float* __restrict__ W, const float* __restrict__ b,
    float* __restrict__ out, int n_nodes)
{
    __shared__ float4 hz[16][64];   // 16 nodes x 256 floats (h | z)
    int n0  = blockIdx.x * 16;
    int tid = threadIdx.x;
    #pragma unroll
    for (int it = 0; it < 4; ++it) {
        int idx = tid + it * 256;       // 0..1023
        int n   = idx >> 6;
        int q   = idx & 63;
        int node = n0 + n;
        float4 v = make_float4(0.f, 0.f, 0.f, 0.f);
        if (node < n_nodes) {
            if (q < 32) v = *reinterpret_cast<const float4*>(h + (size_t)node * DD + q * 4);
            else        v = *reinterpret_cast<const float4*>(u + (size_t)node * DD + (q - 32) * 4);
        }
        hz[n][q] = v;
    }
    __syncthreads();

    int k = tid & 127;
    int g = tid >> 7;
    float acc[8] = {0.f, 0.f, 0.f, 0.f, 0.f, 0.f, 0.f, 0.f};
    const float* wr = W + (size_t)k * (2 * DD);
    #pragma unroll 4
    for (int q = 0; q < 64; ++q) {
        float4 w4 = *reinterpret_cast<const float4*>(wr + q * 4);
        #pragma unroll
        for (int i = 0; i < 8; ++i) {
            float4 x = hz[g * 8 + i][q];   // broadcast across wave
            acc[i] = fmaf(w4.x, x.x, fmaf(w4.y, x.y, fmaf(w4.z, x.z, fmaf(w4.w, x.w, acc[i]))));
        }
    }
    float bk = b[k];
    #pragma unroll
    for (int i = 0; i < 8; ++i) {
        int node = n0 + g * 8 + i;
        if (node < n_nodes)
            out[(size_t)node * DD + k] = fmaxf(acc[i] + bk, 0.f);
    }
}

// ---------------------------------------------------------------------------
extern "C" void kernel_launch(void* const* d_in, const int* in_sizes, int n_in,
                              void* d_out, int out_size, void* d_ws, size_t ws_size,
                              hipStream_t stream)
{
    const float* nfeats = (const float*)d_in[0];
    const float* efeats = (const float*)d_in[1];
    const float* W      = (const float*)d_in[2];
    const float* Wb     = (const float*)d_in[3];
    const float* attn_w = (const float*)d_in[4];
    const float* attn_b = (const float*)d_in[5];
    const int*   src    = (const int*)d_in[6];
    const int*   dst    = (const int*)d_in[7];

    const int n_nodes = in_sizes[0] / DD;
    const int n_edges = in_sizes[6];
    const int NB = (n_nodes + 255) / 256;    // scan blocks

    // workspace layout
    char* wsb = (char*)d_ws;
    float* s_buf  = (float*)wsb;                         wsb += (size_t)n_nodes * 4;
    float* t_buf  = (float*)wsb;                         wsb += (size_t)n_nodes * 4;
    int*   count  = (int*)wsb;                           wsb += (size_t)n_nodes * 4;
    int*   offset = (int*)wsb;                           wsb += (size_t)(n_nodes + 1) * 4;
    int*   bsum   = (int*)wsb;                           wsb += (size_t)((NB + 63) & ~63) * 4;
    int*   order  = (int*)wsb;                           wsb += (size_t)n_edges * 4;
    float* p_buf  = (float*)wsb;                         wsb += (size_t)n_edges * 4;
    float* u_buf  = (float*)wsb;                         // N*128 f32
    int*   rank   = (int*)u_buf;                         // aliased: dead before u written

    (void)hipMemsetAsync(count, 0, (size_t)n_nodes * 4, stream);

    k_node_dots<<<(n_nodes + 3) / 4, 256, 0, stream>>>(nfeats, attn_w, s_buf, t_buf, n_nodes);
    k_hist<<<(n_edges + 255) / 256, 256, 0, stream>>>(dst, count, rank, n_edges);
    k_scan_bsum<<<NB, 256, 0, stream>>>(count, bsum, n_nodes);
    k_scan_carry<<<1, 256, 0, stream>>>(bsum, NB, offset, n_nodes, n_edges);
    k_scan_final<<<NB, 256, 0, stream>>>(count, bsum, offset, n_nodes);
    k_scatter_ids<<<(n_edges + 255) / 256, 256, 0, stream>>>(dst, src, rank, offset,
                                                             s_buf, t_buf, attn_b,
                                                             order, p_buf, n_edges);

    k_fused<<<(n_nodes + 3) / 4, 256, 0, stream>>>(offset, order, efeats, p_buf, u_buf, n_nodes);

    k_apply<<<(n_nodes + 15) / 16, 256, 0, stream>>>(nfeats, u_buf, W, Wb, (float*)d_out, n_nodes);
}